// Round 1
// baseline (4116.663 us; speedup 1.0000x reference)
//
#include <hip/hip_runtime.h>

// ---------------------------------------------------------------------------
// GIN forward: z1 = (1+eps)x + segsum(x); h1 = relu(z1 W1a + b1a);
// h = relu(h1 W1b + b1b); z2 = h + segsum(h); h2 = relu(z2 W2 + b2);
// out = h2 W3 + b3.
// Strategy: fp32 atomics for aggregation (bf16 gather source), bf16 MFMA GEMMs
// (128x128 tile, BK=32, global_load_lds staging, B pre-transposed on device).
// ---------------------------------------------------------------------------

typedef __attribute__((ext_vector_type(8))) short bf16x8;
typedef __attribute__((ext_vector_type(4))) float f32x4;

__device__ __forceinline__ float bf2f(unsigned short u) {
  unsigned v = ((unsigned)u) << 16;
  return __builtin_bit_cast(float, v);
}
__device__ __forceinline__ unsigned short f2bf(float f) {
  unsigned u = __builtin_bit_cast(unsigned, f);
  u += 0x7fffu + ((u >> 16) & 1u);
  return (unsigned short)(u >> 16);
}

// async global->LDS, 16B per lane; LDS dest = wave-uniform base + lane*16
__device__ __forceinline__ void async16(const void* g, void* l) {
  __builtin_amdgcn_global_load_lds(
      (const __attribute__((address_space(1))) void*)g,
      (__attribute__((address_space(3))) void*)l, 16, 0, 0);
}

// --- z1 = (1+eps)*x (fp32), xb = bf16(x) ----------------------------------
__global__ __launch_bounds__(256) void k_prep(const float* __restrict__ x,
    const float* __restrict__ eps, float* __restrict__ z1,
    unsigned short* __restrict__ xb, int n4)
{
  int i = blockIdx.x * 256 + threadIdx.x;
  if (i >= n4) return;
  float s = 1.0f + eps[0];
  float4 v = reinterpret_cast<const float4*>(x)[i];
  float4 z; z.x = v.x * s; z.y = v.y * s; z.z = v.z * s; z.w = v.w * s;
  reinterpret_cast<float4*>(z1)[i] = z;
  ushort4 b; b.x = f2bf(v.x); b.y = f2bf(v.y); b.z = f2bf(v.z); b.w = f2bf(v.w);
  reinterpret_cast<ushort4*>(xb)[i] = b;
}

// --- fp32 -> bf16 cast -----------------------------------------------------
__global__ __launch_bounds__(256) void k_cvt(const float* __restrict__ in,
    unsigned short* __restrict__ out, int n4)
{
  int i = blockIdx.x * 256 + threadIdx.x;
  if (i >= n4) return;
  float4 v = reinterpret_cast<const float4*>(in)[i];
  ushort4 b; b.x = f2bf(v.x); b.y = f2bf(v.y); b.z = f2bf(v.z); b.w = f2bf(v.w);
  reinterpret_cast<ushort4*>(out)[i] = b;
}

// --- W [K][N] fp32 -> WT [N][K] bf16 --------------------------------------
__global__ __launch_bounds__(256) void k_wcvt(const float* __restrict__ W,
    unsigned short* __restrict__ WT, int K, int N)
{
  int idx = blockIdx.x * 256 + threadIdx.x;
  if (idx >= K * N) return;
  int n = idx / K, k = idx - n * K;
  WT[idx] = f2bf(W[k * N + n]);
}

// --- edge aggregation: accum[dst] += feat[src], fp32 atomics ---------------
template<int C>
__global__ __launch_bounds__(256) void k_agg(const int* __restrict__ ei,
    const unsigned short* __restrict__ feat, float* __restrict__ accum, int E)
{
  constexpr int TPE = C / 4;              // threads per edge
  int tid = blockIdx.x * 256 + threadIdx.x;
  int e = tid / TPE;
  if (e >= E) return;
  int c4 = (tid % TPE) * 4;
  int src = ei[e];
  int dst = ei[E + e];
  ushort4 v = *reinterpret_cast<const ushort4*>(feat + (size_t)src * C + c4);
  float* o = accum + (size_t)dst * C + c4;
  atomicAdd(o + 0, bf2f(v.x));
  atomicAdd(o + 1, bf2f(v.y));
  atomicAdd(o + 2, bf2f(v.z));
  atomicAdd(o + 3, bf2f(v.w));
}

// --- bf16 MFMA GEMM: C = A[M][K] * BT[N][K]^T + bias, optional relu --------
// MODE 0: bf16 out; 1: bf16 + fp32 out; 2: fp32 out
template<bool RELU, int MODE>
__global__ __launch_bounds__(256) void k_gemm(
    const unsigned short* __restrict__ A,
    const unsigned short* __restrict__ BT,
    const float* __restrict__ bias,
    unsigned short* __restrict__ Cb,
    float* __restrict__ Cf,
    int M, int K, int N)
{
  __shared__ unsigned short Asb[128 * 32];
  __shared__ unsigned short Bsb[128 * 32];
  const int tid = threadIdx.x;
  const int w = tid >> 6, l = tid & 63;
  const int bm = blockIdx.x * 128, bn = blockIdx.y * 128;
  const int wr = w >> 1, wc = w & 1;

  f32x4 acc[4][4];
#pragma unroll
  for (int m = 0; m < 4; m++)
#pragma unroll
    for (int n = 0; n < 4; n++) acc[m][n] = (f32x4)(0.0f);

  const int lr = l >> 2;          // row within a 16-row staging chunk
  const int lc = (l & 3) * 8;     // bf16 col offset within BK=32

  for (int kt = 0; kt < K; kt += 32) {
    __syncthreads();
#pragma unroll
    for (int i = 0; i < 2; i++) {
      int tr = w * 32 + i * 16;                    // chunk base row (wave-uniform)
      int ar = bm + tr + lr; if (ar >= M) ar = M - 1;
      async16(A + (size_t)ar * K + kt + lc, &Asb[tr * 32]);
      int br = bn + tr + lr;                       // always < N (N % 128 == 0)
      async16(BT + (size_t)br * K + kt + lc, &Bsb[tr * 32]);
    }
    __syncthreads();

    bf16x8 af[4], bfr[4];
#pragma unroll
    for (int m = 0; m < 4; m++)
      af[m] = *reinterpret_cast<const bf16x8*>(
          &Asb[(wr * 64 + m * 16 + (l & 15)) * 32 + (l >> 4) * 8]);
#pragma unroll
    for (int n = 0; n < 4; n++)
      bfr[n] = *reinterpret_cast<const bf16x8*>(
          &Bsb[(wc * 64 + n * 16 + (l & 15)) * 32 + (l >> 4) * 8]);
#pragma unroll
    for (int m = 0; m < 4; m++)
#pragma unroll
      for (int n = 0; n < 4; n++)
        acc[m][n] = __builtin_amdgcn_mfma_f32_16x16x32_bf16(
            af[m], bfr[n], acc[m][n], 0, 0, 0);
  }

  // epilogue: C/D layout col = lane&15, row = (lane>>4)*4 + reg  [m89]
#pragma unroll
  for (int m = 0; m < 4; m++) {
    int row0 = bm + wr * 64 + m * 16 + ((l >> 4) << 2);
#pragma unroll
    for (int n = 0; n < 4; n++) {
      int col = bn + wc * 64 + n * 16 + (l & 15);
      float bv = bias[col];
#pragma unroll
      for (int r = 0; r < 4; r++) {
        int row = row0 + r;
        if (row < M) {
          float v = acc[m][n][r] + bv;
          if (RELU) v = fmaxf(v, 0.0f);
          if (MODE == 0 || MODE == 1) Cb[(size_t)row * N + col] = f2bf(v);
          if (MODE == 1 || MODE == 2) Cf[(size_t)row * N + col] = v;
        }
      }
    }
  }
}

// ---------------------------------------------------------------------------
// workspace layout (overlapped lifetimes; total need = 115,593,216 B)
static const size_t OFF_Z1  = 0;           // f32 [50000][128]  (dead after cvt1)
static const size_t OFF_Z2  = 0;           // f32 [50000][256]  (written by gemm2)
static const size_t OFF_XB  = 51200000;    // bf16 [50000][128] (dead after agg1)
static const size_t OFF_Z1B = 51200000;    // bf16 [50000][128] (cvt1 -> gemm1)
static const size_t OFF_H1B = 64000000;    // bf16 [50000][256] (gemm1 -> gemm2)
static const size_t OFF_HB  = 89600000;    // bf16 [50000][256] (gemm2 -> agg2)
static const size_t OFF_Z2B = 51200000;    // bf16 [50000][256] (cvt2 -> gemm3)
static const size_t OFF_H2B = 89600000;    // bf16 [50000][256] (gemm3 -> gemm4)
static const size_t OFF_WT  = 115200000;   // bf16 weights, 393,216 B

extern "C" void kernel_launch(void* const* d_in, const int* in_sizes, int n_in,
                              void* d_out, int out_size, void* d_ws, size_t ws_size,
                              hipStream_t stream)
{
  const float* x    = (const float*)d_in[0];
  const int*   ei   = (const int*)d_in[1];
  const float* W1a  = (const float*)d_in[2];
  const float* b1a  = (const float*)d_in[3];
  const float* W1b  = (const float*)d_in[4];
  const float* b1b  = (const float*)d_in[5];
  const float* eps1 = (const float*)d_in[6];
  const float* W2   = (const float*)d_in[7];
  const float* b2   = (const float*)d_in[8];
  const float* W3   = (const float*)d_in[9];
  const float* b3   = (const float*)d_in[10];

  char* ws = (char*)d_ws;
  float*          z1   = (float*)(ws + OFF_Z1);
  float*          z2   = (float*)(ws + OFF_Z2);
  unsigned short* xb   = (unsigned short*)(ws + OFF_XB);
  unsigned short* z1b  = (unsigned short*)(ws + OFF_Z1B);
  unsigned short* h1b  = (unsigned short*)(ws + OFF_H1B);
  unsigned short* hb   = (unsigned short*)(ws + OFF_HB);
  unsigned short* z2b  = (unsigned short*)(ws + OFF_Z2B);
  unsigned short* h2b  = (unsigned short*)(ws + OFF_H2B);
  unsigned short* wt   = (unsigned short*)(ws + OFF_WT);
  unsigned short* w1at = wt;                 // [256][128]
  unsigned short* w1bt = wt + 32768;         // [256][256]
  unsigned short* w2t  = wt + 98304;         // [256][256]
  unsigned short* w3t  = wt + 163840;        // [128][256]

  // weight transpose+cast (tiny)
  k_wcvt<<<(128 * 256 + 255) / 256, 256, 0, stream>>>(W1a, w1at, 128, 256);
  k_wcvt<<<(256 * 256 + 255) / 256, 256, 0, stream>>>(W1b, w1bt, 256, 256);
  k_wcvt<<<(256 * 256 + 255) / 256, 256, 0, stream>>>(W2,  w2t,  256, 256);
  k_wcvt<<<(256 * 128 + 255) / 256, 256, 0, stream>>>(W3,  w3t,  256, 128);

  const int NN = 50000, NE = 800000;
  int n4a = NN * 128 / 4;                    // 1.6M
  k_prep<<<(n4a + 255) / 256, 256, 0, stream>>>(x, eps1, z1, xb, n4a);
  k_agg<128><<<(NE * 32) / 256, 256, 0, stream>>>(ei, xb, z1, NE);
  k_cvt<<<(n4a + 255) / 256, 256, 0, stream>>>(z1, z1b, n4a);

  dim3 g1(391, 2);
  k_gemm<true, 0><<<g1, 256, 0, stream>>>(z1b, w1at, b1a, h1b, nullptr, NN, 128, 256);
  k_gemm<true, 1><<<g1, 256, 0, stream>>>(h1b, w1bt, b1b, hb, z2, NN, 256, 256);

  k_agg<256><<<(NE * 64) / 256, 256, 0, stream>>>(ei, hb, z2, NE);
  int n4b = NN * 256 / 4;                    // 3.2M
  k_cvt<<<(n4b + 255) / 256, 256, 0, stream>>>(z2, z2b, n4b);

  k_gemm<true, 0><<<g1, 256, 0, stream>>>(z2b, w2t, b2, h2b, nullptr, NN, 256, 256);
  dim3 g4(391, 1);
  k_gemm<false, 2><<<g4, 256, 0, stream>>>(h2b, w3t, b3, nullptr, (float*)d_out, NN, 256, 128);
}

// Round 2
// 385.024 us; speedup vs baseline: 10.6920x; 10.6920x over previous
//
#include <hip/hip_runtime.h>

// ---------------------------------------------------------------------------
// GIN forward. R2: replace fp32-atomic scatter aggregation (3.28 GB HBM
// write-through, 2.6ms+1.3ms) with on-device CSR build + per-node gather
// (fp32 register accumulation, bf16 in/out, self-term fused).
// GEMMs: bf16 MFMA, 128x128 tile, BK=32, global_load_lds staging.
// ---------------------------------------------------------------------------

typedef __attribute__((ext_vector_type(8))) short bf16x8;
typedef __attribute__((ext_vector_type(4))) float f32x4;

__device__ __forceinline__ float bf2f(unsigned short u) {
  unsigned v = ((unsigned)u) << 16;
  return __builtin_bit_cast(float, v);
}
__device__ __forceinline__ unsigned short f2bf(float f) {
  unsigned u = __builtin_bit_cast(unsigned, f);
  u += 0x7fffu + ((u >> 16) & 1u);
  return (unsigned short)(u >> 16);
}

__device__ __forceinline__ void async16(const void* g, void* l) {
  __builtin_amdgcn_global_load_lds(
      (const __attribute__((address_space(1))) void*)g,
      (__attribute__((address_space(3))) void*)l, 16, 0, 0);
}

static const int NN = 50000;
static const int NE = 800000;

// --- fp32 -> bf16 cast -----------------------------------------------------
__global__ __launch_bounds__(256) void k_cvt(const float* __restrict__ in,
    unsigned short* __restrict__ out, int n4)
{
  int i = blockIdx.x * 256 + threadIdx.x;
  if (i >= n4) return;
  float4 v = reinterpret_cast<const float4*>(in)[i];
  ushort4 b; b.x = f2bf(v.x); b.y = f2bf(v.y); b.z = f2bf(v.z); b.w = f2bf(v.w);
  reinterpret_cast<ushort4*>(out)[i] = b;
}

// --- W [K][N] fp32 -> WT [N][K] bf16 --------------------------------------
__global__ __launch_bounds__(256) void k_wcvt(const float* __restrict__ W,
    unsigned short* __restrict__ WT, int K, int N)
{
  int idx = blockIdx.x * 256 + threadIdx.x;
  if (idx >= K * N) return;
  int n = idx / K, k = idx - n * K;
  WT[idx] = f2bf(W[k * N + n]);
}

// --- CSR build: histogram over dst ----------------------------------------
__global__ __launch_bounds__(256) void k_hist(const int* __restrict__ ei,
    int* __restrict__ counts)
{
  int e = blockIdx.x * 256 + threadIdx.x;
  if (e >= NE) return;
  atomicAdd(&counts[ei[NE + e]], 1);
}

// --- exclusive scan over 50000 counts (single block, 1024 thr) -------------
// in: counts[]; out: offs[0..NN] and counts[] rewritten to exclusive prefix
// (reused as the scatter cursor).
__global__ __launch_bounds__(1024) void k_scan(int* __restrict__ counts,
    int* __restrict__ offs)
{
  __shared__ int tot[1024];
  const int t = threadIdx.x;
  const int CH = 49;                      // 1024*49 = 50176 >= 50000
  int loc[CH];
  int base = t * CH;
  int s = 0;
#pragma unroll
  for (int j = 0; j < CH; j++) {
    int idx = base + j;
    int c = (idx < NN) ? counts[idx] : 0;
    loc[j] = s; s += c;
  }
  tot[t] = s;
  __syncthreads();
  for (int off = 1; off < 1024; off <<= 1) {
    int v = (t >= off) ? tot[t - off] : 0;
    __syncthreads();
    tot[t] += v;
    __syncthreads();
  }
  int ex = tot[t] - s;                    // exclusive prefix of this thread
#pragma unroll
  for (int j = 0; j < CH; j++) {
    int idx = base + j;
    if (idx < NN) { offs[idx] = ex + loc[j]; counts[idx] = ex + loc[j]; }
  }
  if (t == 1023) offs[NN] = tot[1023];
}

// --- scatter src ids into CSR order ---------------------------------------
__global__ __launch_bounds__(256) void k_scatter(const int* __restrict__ ei,
    int* __restrict__ cursor, int* __restrict__ srcs)
{
  int e = blockIdx.x * 256 + threadIdx.x;
  if (e >= NE) return;
  int dst = ei[NE + e];
  int pos = atomicAdd(&cursor[dst], 1);
  srcs[pos] = ei[e];
}

// --- gather-aggregate: out[n] = bf16(self(n) + sum_{s in N(n)} feat[s]) ----
// L1: self = (1+eps)*x_fp32 ; else self = feat-type bf16 row.
template<int C, bool L1>
__global__ __launch_bounds__(256) void k_gather(const int* __restrict__ offs,
    const int* __restrict__ srcs, const unsigned short* __restrict__ feat,
    const void* __restrict__ selfp, const float* __restrict__ eps,
    unsigned short* __restrict__ out)
{
  constexpr int TPN = C / 4;              // lanes per node (32 or 64)
  int tid = blockIdx.x * 256 + threadIdx.x;
  int node = tid / TPN;
  if (node >= NN) return;
  int c4 = (tid % TPN) * 4;

  float ax, ay, az, aw;
  if (L1) {
    float sc = 1.0f + eps[0];
    const float* sx = (const float*)selfp;
    float4 v = *reinterpret_cast<const float4*>(sx + (size_t)node * C + c4);
    ax = v.x * sc; ay = v.y * sc; az = v.z * sc; aw = v.w * sc;
  } else {
    const unsigned short* sh = (const unsigned short*)selfp;
    ushort4 v = *reinterpret_cast<const ushort4*>(sh + (size_t)node * C + c4);
    ax = bf2f(v.x); ay = bf2f(v.y); az = bf2f(v.z); aw = bf2f(v.w);
  }

  int beg = offs[node], end = offs[node + 1];
  int i = beg;
  for (; i + 2 <= end; i += 2) {
    int s0 = srcs[i], s1 = srcs[i + 1];
    ushort4 v0 = *reinterpret_cast<const ushort4*>(feat + (size_t)s0 * C + c4);
    ushort4 v1 = *reinterpret_cast<const ushort4*>(feat + (size_t)s1 * C + c4);
    ax += bf2f(v0.x); ay += bf2f(v0.y); az += bf2f(v0.z); aw += bf2f(v0.w);
    ax += bf2f(v1.x); ay += bf2f(v1.y); az += bf2f(v1.z); aw += bf2f(v1.w);
  }
  if (i < end) {
    int s0 = srcs[i];
    ushort4 v0 = *reinterpret_cast<const ushort4*>(feat + (size_t)s0 * C + c4);
    ax += bf2f(v0.x); ay += bf2f(v0.y); az += bf2f(v0.z); aw += bf2f(v0.w);
  }

  ushort4 o; o.x = f2bf(ax); o.y = f2bf(ay); o.z = f2bf(az); o.w = f2bf(aw);
  *reinterpret_cast<ushort4*>(out + (size_t)node * C + c4) = o;
}

// --- bf16 MFMA GEMM: C = A[M][K] * BT[N][K]^T + bias, optional relu --------
// MODE 0: bf16 out; 2: fp32 out
template<bool RELU, int MODE>
__global__ __launch_bounds__(256) void k_gemm(
    const unsigned short* __restrict__ A,
    const unsigned short* __restrict__ BT,
    const float* __restrict__ bias,
    unsigned short* __restrict__ Cb,
    float* __restrict__ Cf,
    int M, int K, int N)
{
  __shared__ unsigned short Asb[128 * 32];
  __shared__ unsigned short Bsb[128 * 32];
  const int tid = threadIdx.x;
  const int w = tid >> 6, l = tid & 63;
  const int bm = blockIdx.x * 128, bn = blockIdx.y * 128;
  const int wr = w >> 1, wc = w & 1;

  f32x4 acc[4][4];
#pragma unroll
  for (int m = 0; m < 4; m++)
#pragma unroll
    for (int n = 0; n < 4; n++) acc[m][n] = (f32x4)(0.0f);

  const int lr = l >> 2;
  const int lc = (l & 3) * 8;

  for (int kt = 0; kt < K; kt += 32) {
    __syncthreads();
#pragma unroll
    for (int i = 0; i < 2; i++) {
      int tr = w * 32 + i * 16;
      int ar = bm + tr + lr; if (ar >= M) ar = M - 1;
      async16(A + (size_t)ar * K + kt + lc, &Asb[tr * 32]);
      int br = bn + tr + lr;
      async16(BT + (size_t)br * K + kt + lc, &Bsb[tr * 32]);
    }
    __syncthreads();

    bf16x8 af[4], bfr[4];
#pragma unroll
    for (int m = 0; m < 4; m++)
      af[m] = *reinterpret_cast<const bf16x8*>(
          &Asb[(wr * 64 + m * 16 + (l & 15)) * 32 + (l >> 4) * 8]);
#pragma unroll
    for (int n = 0; n < 4; n++)
      bfr[n] = *reinterpret_cast<const bf16x8*>(
          &Bsb[(wc * 64 + n * 16 + (l & 15)) * 32 + (l >> 4) * 8]);
#pragma unroll
    for (int m = 0; m < 4; m++)
#pragma unroll
      for (int n = 0; n < 4; n++)
        acc[m][n] = __builtin_amdgcn_mfma_f32_16x16x32_bf16(
            af[m], bfr[n], acc[m][n], 0, 0, 0);
  }

#pragma unroll
  for (int m = 0; m < 4; m++) {
    int row0 = bm + wr * 64 + m * 16 + ((l >> 4) << 2);
#pragma unroll
    for (int n = 0; n < 4; n++) {
      int col = bn + wc * 64 + n * 16 + (l & 15);
      float bv = bias[col];
#pragma unroll
      for (int r = 0; r < 4; r++) {
        int row = row0 + r;
        if (row < M) {
          float v = acc[m][n][r] + bv;
          if (RELU) v = fmaxf(v, 0.0f);
          if (MODE == 0) Cb[(size_t)row * N + col] = f2bf(v);
          if (MODE == 2) Cf[(size_t)row * N + col] = v;
        }
      }
    }
  }
}

// ---------------------------------------------------------------------------
// workspace layout (bytes); overlapped lifetimes:
//  xb   [ 0.0 .. 12.8M)  bf16 x        (cvt -> gather1)
//  z1b  [12.8 .. 25.6M)  bf16 z1       (gather1 -> gemm1)
//  h1b  [25.6 .. 51.2M)  bf16 h1       (gemm1 -> gemm2)
//  hb   [51.2 .. 76.8M)  bf16 h        (gemm2 -> gather2)
//  z2b  [ 0.0 .. 25.6M)  bf16 z2       (gather2 -> gemm3)   over xb+z1b (dead)
//  h2b  [25.6 .. 51.2M)  bf16 h2       (gemm3 -> gemm4)     over h1b (dead)
//  CSR  [76.8M ..)       offs[50001], cursor/counts[50000], srcs[800000]
//  WT   [81.0M ..)       bf16 weights
static const size_t OFF_XB   = 0;
static const size_t OFF_Z1B  = 12800000;
static const size_t OFF_H1B  = 25600000;
static const size_t OFF_HB   = 51200000;
static const size_t OFF_Z2B  = 0;
static const size_t OFF_H2B  = 25600000;
static const size_t OFF_OFFS = 76800000;           // 50001 ints -> 200064 B
static const size_t OFF_CNT  = 77000064;           // 50000 ints -> 200064 B
static const size_t OFF_SRC  = 77200128;           // 800000 ints -> 3.2 MB
static const size_t OFF_WT   = 80400128;           // 393216 B

extern "C" void kernel_launch(void* const* d_in, const int* in_sizes, int n_in,
                              void* d_out, int out_size, void* d_ws, size_t ws_size,
                              hipStream_t stream)
{
  const float* x    = (const float*)d_in[0];
  const int*   ei   = (const int*)d_in[1];
  const float* W1a  = (const float*)d_in[2];
  const float* b1a  = (const float*)d_in[3];
  const float* W1b  = (const float*)d_in[4];
  const float* b1b  = (const float*)d_in[5];
  const float* eps1 = (const float*)d_in[6];
  const float* W2   = (const float*)d_in[7];
  const float* b2   = (const float*)d_in[8];
  const float* W3   = (const float*)d_in[9];
  const float* b3   = (const float*)d_in[10];

  char* ws = (char*)d_ws;
  unsigned short* xb   = (unsigned short*)(ws + OFF_XB);
  unsigned short* z1b  = (unsigned short*)(ws + OFF_Z1B);
  unsigned short* h1b  = (unsigned short*)(ws + OFF_H1B);
  unsigned short* hb   = (unsigned short*)(ws + OFF_HB);
  unsigned short* z2b  = (unsigned short*)(ws + OFF_Z2B);
  unsigned short* h2b  = (unsigned short*)(ws + OFF_H2B);
  int*            offs = (int*)(ws + OFF_OFFS);
  int*            cnts = (int*)(ws + OFF_CNT);
  int*            srcs = (int*)(ws + OFF_SRC);
  unsigned short* wt   = (unsigned short*)(ws + OFF_WT);
  unsigned short* w1at = wt;                 // [256][128]
  unsigned short* w1bt = wt + 32768;         // [256][256]
  unsigned short* w2t  = wt + 98304;         // [256][256]
  unsigned short* w3t  = wt + 163840;        // [128][256]

  // weights (tiny)
  k_wcvt<<<(128 * 256 + 255) / 256, 256, 0, stream>>>(W1a, w1at, 128, 256);
  k_wcvt<<<(256 * 256 + 255) / 256, 256, 0, stream>>>(W1b, w1bt, 256, 256);
  k_wcvt<<<(256 * 256 + 255) / 256, 256, 0, stream>>>(W2,  w2t,  256, 256);
  k_wcvt<<<(256 * 128 + 255) / 256, 256, 0, stream>>>(W3,  w3t,  256, 128);

  // CSR build
  hipMemsetAsync(cnts, 0, 50000 * sizeof(int), stream);
  k_hist<<<(NE + 255) / 256, 256, 0, stream>>>(ei, cnts);
  k_scan<<<1, 1024, 0, stream>>>(cnts, offs);
  k_scatter<<<(NE + 255) / 256, 256, 0, stream>>>(ei, cnts, srcs);

  // x -> bf16
  k_cvt<<<(NN * 128 / 4 + 255) / 256, 256, 0, stream>>>(x, xb, NN * 128 / 4);

  // layer 1
  k_gather<128, true><<<(NN * 32 + 255) / 256, 256, 0, stream>>>(
      offs, srcs, xb, x, eps1, z1b);
  dim3 g1(391, 2);
  k_gemm<true, 0><<<g1, 256, 0, stream>>>(z1b, w1at, b1a, h1b, nullptr, NN, 128, 256);
  k_gemm<true, 0><<<g1, 256, 0, stream>>>(h1b, w1bt, b1b, hb, nullptr, NN, 256, 256);

  // layer 2
  k_gather<256, false><<<(NN * 64 + 255) / 256, 256, 0, stream>>>(
      offs, srcs, hb, hb, nullptr, z2b);
  k_gemm<true, 0><<<g1, 256, 0, stream>>>(z2b, w2t, b2, h2b, nullptr, NN, 256, 256);
  dim3 g4(391, 1);
  k_gemm<false, 2><<<g4, 256, 0, stream>>>(h2b, w3t, b3, nullptr, (float*)d_out, NN, 256, 128);
}

// Round 3
// 297.870 us; speedup vs baseline: 13.8203x; 1.2926x over previous
//
#include <hip/hip_runtime.h>

// ---------------------------------------------------------------------------
// GIN forward. R3: parallelize the CSR prefix scan (was a single-block 82µs
// kernel = 21% of runtime) into a 2-kernel block-scan + apply; merge the 4
// weight-transpose launches into one.
// Aggregation: on-device CSR build + per-node gather (fp32 reg accumulation,
// bf16 in/out, self-term fused). GEMMs: bf16 MFMA, 128x128 tile, BK=32,
// global_load_lds staging.
// ---------------------------------------------------------------------------

typedef __attribute__((ext_vector_type(8))) short bf16x8;
typedef __attribute__((ext_vector_type(4))) float f32x4;

__device__ __forceinline__ float bf2f(unsigned short u) {
  unsigned v = ((unsigned)u) << 16;
  return __builtin_bit_cast(float, v);
}
__device__ __forceinline__ unsigned short f2bf(float f) {
  unsigned u = __builtin_bit_cast(unsigned, f);
  u += 0x7fffu + ((u >> 16) & 1u);
  return (unsigned short)(u >> 16);
}

__device__ __forceinline__ void async16(const void* g, void* l) {
  __builtin_amdgcn_global_load_lds(
      (const __attribute__((address_space(1))) void*)g,
      (__attribute__((address_space(3))) void*)l, 16, 0, 0);
}

static const int NN = 50000;
static const int NE = 800000;
static const int SCAN_NB = 49;             // ceil(50000/1024)

// --- fp32 -> bf16 cast -----------------------------------------------------
__global__ __launch_bounds__(256) void k_cvt(const float* __restrict__ in,
    unsigned short* __restrict__ out, int n4)
{
  int i = blockIdx.x * 256 + threadIdx.x;
  if (i >= n4) return;
  float4 v = reinterpret_cast<const float4*>(in)[i];
  ushort4 b; b.x = f2bf(v.x); b.y = f2bf(v.y); b.z = f2bf(v.z); b.w = f2bf(v.w);
  reinterpret_cast<ushort4*>(out)[i] = b;
}

// --- all four weights: W [K][N] fp32 -> WT [N][K] bf16, one launch ---------
__global__ __launch_bounds__(256) void k_wcvt_all(
    const float* __restrict__ W1a, const float* __restrict__ W1b,
    const float* __restrict__ W2,  const float* __restrict__ W3,
    unsigned short* __restrict__ WT)
{
  int idx = blockIdx.x * 256 + threadIdx.x;   // 0 .. 196607
  const float* W; unsigned short* out; int K, N, li;
  if (idx < 32768)        { W = W1a; out = WT;          K = 128; N = 256; li = idx; }
  else if (idx < 98304)   { W = W1b; out = WT + 32768;  K = 256; N = 256; li = idx - 32768; }
  else if (idx < 163840)  { W = W2;  out = WT + 98304;  K = 256; N = 256; li = idx - 98304; }
  else if (idx < 196608)  { W = W3;  out = WT + 163840; K = 256; N = 128; li = idx - 163840; }
  else return;
  int n = li / K, k = li - n * K;
  out[li] = f2bf(W[k * N + n]);
}

// --- CSR build: histogram over dst ----------------------------------------
__global__ __launch_bounds__(256) void k_hist(const int* __restrict__ ei,
    int* __restrict__ counts)
{
  int e = blockIdx.x * 256 + threadIdx.x;
  if (e >= NE) return;
  atomicAdd(&counts[ei[NE + e]], 1);
}

// --- scan phase A: per-block inclusive scan (Hillis-Steele in LDS) ---------
// offs[idx] <- block-local EXCLUSIVE prefix; bsum[blk] <- block total
__global__ __launch_bounds__(1024) void k_scan_a(const int* __restrict__ counts,
    int* __restrict__ offs, int* __restrict__ bsum)
{
  __shared__ int sh[1024];
  const int t = threadIdx.x;
  int idx = blockIdx.x * 1024 + t;
  int c = (idx < NN) ? counts[idx] : 0;
  sh[t] = c;
  __syncthreads();
  int v = c;
  for (int off = 1; off < 1024; off <<= 1) {
    int tmp = (t >= off) ? sh[t - off] : 0;
    __syncthreads();
    v += tmp; sh[t] = v;
    __syncthreads();
  }
  if (idx < NN) offs[idx] = v - c;
  if (t == 1023) bsum[blockIdx.x] = v;
}

// --- scan phase B: add block bases; copy to cursor; offs[NN]=NE ------------
__global__ __launch_bounds__(1024) void k_scan_b(const int* __restrict__ bsum,
    int* __restrict__ offs, int* __restrict__ cursor)
{
  __shared__ int sb[64];
  const int t = threadIdx.x;
  if (t < SCAN_NB) sb[t] = bsum[t];
  __syncthreads();
  int base = 0;
  for (int j = 0; j < SCAN_NB; j++) base += (j < (int)blockIdx.x) ? sb[j] : 0;
  int idx = blockIdx.x * 1024 + t;
  if (idx < NN) { int o = offs[idx] + base; offs[idx] = o; cursor[idx] = o; }
  if (blockIdx.x == 0 && t == 0) offs[NN] = NE;
}

// --- scatter src ids into CSR order ---------------------------------------
__global__ __launch_bounds__(256) void k_scatter(const int* __restrict__ ei,
    int* __restrict__ cursor, int* __restrict__ srcs)
{
  int e = blockIdx.x * 256 + threadIdx.x;
  if (e >= NE) return;
  int dst = ei[NE + e];
  int pos = atomicAdd(&cursor[dst], 1);
  srcs[pos] = ei[e];
}

// --- gather-aggregate: out[n] = bf16(self(n) + sum_{s in N(n)} feat[s]) ----
// L1: self = (1+eps)*x_fp32 ; else self = feat-type bf16 row.
template<int C, bool L1>
__global__ __launch_bounds__(256) void k_gather(const int* __restrict__ offs,
    const int* __restrict__ srcs, const unsigned short* __restrict__ feat,
    const void* __restrict__ selfp, const float* __restrict__ eps,
    unsigned short* __restrict__ out)
{
  constexpr int TPN = C / 4;              // lanes per node (32 or 64)
  int tid = blockIdx.x * 256 + threadIdx.x;
  int node = tid / TPN;
  if (node >= NN) return;
  int c4 = (tid % TPN) * 4;

  float ax, ay, az, aw;
  if (L1) {
    float sc = 1.0f + eps[0];
    const float* sx = (const float*)selfp;
    float4 v = *reinterpret_cast<const float4*>(sx + (size_t)node * C + c4);
    ax = v.x * sc; ay = v.y * sc; az = v.z * sc; aw = v.w * sc;
  } else {
    const unsigned short* sh = (const unsigned short*)selfp;
    ushort4 v = *reinterpret_cast<const ushort4*>(sh + (size_t)node * C + c4);
    ax = bf2f(v.x); ay = bf2f(v.y); az = bf2f(v.z); aw = bf2f(v.w);
  }

  int beg = offs[node], end = offs[node + 1];
  int i = beg;
  for (; i + 2 <= end; i += 2) {
    int s0 = srcs[i], s1 = srcs[i + 1];
    ushort4 v0 = *reinterpret_cast<const ushort4*>(feat + (size_t)s0 * C + c4);
    ushort4 v1 = *reinterpret_cast<const ushort4*>(feat + (size_t)s1 * C + c4);
    ax += bf2f(v0.x); ay += bf2f(v0.y); az += bf2f(v0.z); aw += bf2f(v0.w);
    ax += bf2f(v1.x); ay += bf2f(v1.y); az += bf2f(v1.z); aw += bf2f(v1.w);
  }
  if (i < end) {
    int s0 = srcs[i];
    ushort4 v0 = *reinterpret_cast<const ushort4*>(feat + (size_t)s0 * C + c4);
    ax += bf2f(v0.x); ay += bf2f(v0.y); az += bf2f(v0.z); aw += bf2f(v0.w);
  }

  ushort4 o; o.x = f2bf(ax); o.y = f2bf(ay); o.z = f2bf(az); o.w = f2bf(aw);
  *reinterpret_cast<ushort4*>(out + (size_t)node * C + c4) = o;
}

// --- bf16 MFMA GEMM: C = A[M][K] * BT[N][K]^T + bias, optional relu --------
// MODE 0: bf16 out; 2: fp32 out
template<bool RELU, int MODE>
__global__ __launch_bounds__(256) void k_gemm(
    const unsigned short* __restrict__ A,
    const unsigned short* __restrict__ BT,
    const float* __restrict__ bias,
    unsigned short* __restrict__ Cb,
    float* __restrict__ Cf,
    int M, int K, int N)
{
  __shared__ unsigned short Asb[128 * 32];
  __shared__ unsigned short Bsb[128 * 32];
  const int tid = threadIdx.x;
  const int w = tid >> 6, l = tid & 63;
  const int bm = blockIdx.x * 128, bn = blockIdx.y * 128;
  const int wr = w >> 1, wc = w & 1;

  f32x4 acc[4][4];
#pragma unroll
  for (int m = 0; m < 4; m++)
#pragma unroll
    for (int n = 0; n < 4; n++) acc[m][n] = (f32x4)(0.0f);

  const int lr = l >> 2;
  const int lc = (l & 3) * 8;

  for (int kt = 0; kt < K; kt += 32) {
    __syncthreads();
#pragma unroll
    for (int i = 0; i < 2; i++) {
      int tr = w * 32 + i * 16;
      int ar = bm + tr + lr; if (ar >= M) ar = M - 1;
      async16(A + (size_t)ar * K + kt + lc, &Asb[tr * 32]);
      int br = bn + tr + lr;
      async16(BT + (size_t)br * K + kt + lc, &Bsb[tr * 32]);
    }
    __syncthreads();

    bf16x8 af[4], bfr[4];
#pragma unroll
    for (int m = 0; m < 4; m++)
      af[m] = *reinterpret_cast<const bf16x8*>(
          &Asb[(wr * 64 + m * 16 + (l & 15)) * 32 + (l >> 4) * 8]);
#pragma unroll
    for (int n = 0; n < 4; n++)
      bfr[n] = *reinterpret_cast<const bf16x8*>(
          &Bsb[(wc * 64 + n * 16 + (l & 15)) * 32 + (l >> 4) * 8]);
#pragma unroll
    for (int m = 0; m < 4; m++)
#pragma unroll
      for (int n = 0; n < 4; n++)
        acc[m][n] = __builtin_amdgcn_mfma_f32_16x16x32_bf16(
            af[m], bfr[n], acc[m][n], 0, 0, 0);
  }

#pragma unroll
  for (int m = 0; m < 4; m++) {
    int row0 = bm + wr * 64 + m * 16 + ((l >> 4) << 2);
#pragma unroll
    for (int n = 0; n < 4; n++) {
      int col = bn + wc * 64 + n * 16 + (l & 15);
      float bv = bias[col];
#pragma unroll
      for (int r = 0; r < 4; r++) {
        int row = row0 + r;
        if (row < M) {
          float v = acc[m][n][r] + bv;
          if (RELU) v = fmaxf(v, 0.0f);
          if (MODE == 0) Cb[(size_t)row * N + col] = f2bf(v);
          if (MODE == 2) Cf[(size_t)row * N + col] = v;
        }
      }
    }
  }
}

// ---------------------------------------------------------------------------
// workspace layout (bytes); overlapped lifetimes:
//  xb   [ 0.0 .. 12.8M)  bf16 x        (cvt -> gather1)
//  z1b  [12.8 .. 25.6M)  bf16 z1       (gather1 -> gemm1)
//  h1b  [25.6 .. 51.2M)  bf16 h1       (gemm1 -> gemm2)
//  hb   [51.2 .. 76.8M)  bf16 h        (gemm2 -> gather2)
//  z2b  [ 0.0 .. 25.6M)  bf16 z2       (gather2 -> gemm3)   over xb+z1b (dead)
//  h2b  [25.6 .. 51.2M)  bf16 h2       (gemm3 -> gemm4)     over h1b (dead)
//  CSR  [76.8M ..)       offs[50001], cursor/counts[50000], srcs[800000], bsum
//  WT   [81.0M ..)       bf16 weights
static const size_t OFF_XB   = 0;
static const size_t OFF_Z1B  = 12800000;
static const size_t OFF_H1B  = 25600000;
static const size_t OFF_HB   = 51200000;
static const size_t OFF_Z2B  = 0;
static const size_t OFF_H2B  = 25600000;
static const size_t OFF_OFFS = 76800000;           // 50001 ints
static const size_t OFF_CNT  = 77000064;           // 50000 ints
static const size_t OFF_SRC  = 77200128;           // 800000 ints
static const size_t OFF_BSUM = 80400128;           // 64 ints
static const size_t OFF_WT   = 80400512;           // 393216 B

extern "C" void kernel_launch(void* const* d_in, const int* in_sizes, int n_in,
                              void* d_out, int out_size, void* d_ws, size_t ws_size,
                              hipStream_t stream)
{
  const float* x    = (const float*)d_in[0];
  const int*   ei   = (const int*)d_in[1];
  const float* W1a  = (const float*)d_in[2];
  const float* b1a  = (const float*)d_in[3];
  const float* W1b  = (const float*)d_in[4];
  const float* b1b  = (const float*)d_in[5];
  const float* eps1 = (const float*)d_in[6];
  const float* W2   = (const float*)d_in[7];
  const float* b2   = (const float*)d_in[8];
  const float* W3   = (const float*)d_in[9];
  const float* b3   = (const float*)d_in[10];

  char* ws = (char*)d_ws;
  unsigned short* xb   = (unsigned short*)(ws + OFF_XB);
  unsigned short* z1b  = (unsigned short*)(ws + OFF_Z1B);
  unsigned short* h1b  = (unsigned short*)(ws + OFF_H1B);
  unsigned short* hb   = (unsigned short*)(ws + OFF_HB);
  unsigned short* z2b  = (unsigned short*)(ws + OFF_Z2B);
  unsigned short* h2b  = (unsigned short*)(ws + OFF_H2B);
  int*            offs = (int*)(ws + OFF_OFFS);
  int*            cnts = (int*)(ws + OFF_CNT);
  int*            srcs = (int*)(ws + OFF_SRC);
  int*            bsum = (int*)(ws + OFF_BSUM);
  unsigned short* wt   = (unsigned short*)(ws + OFF_WT);
  unsigned short* w1at = wt;                 // [256][128]
  unsigned short* w1bt = wt + 32768;         // [256][256]
  unsigned short* w2t  = wt + 98304;         // [256][256]
  unsigned short* w3t  = wt + 163840;        // [128][256]

  // weights (one launch)
  k_wcvt_all<<<768, 256, 0, stream>>>(W1a, W1b, W2, W3, wt);

  // CSR build
  hipMemsetAsync(cnts, 0, 50000 * sizeof(int), stream);
  k_hist<<<(NE + 255) / 256, 256, 0, stream>>>(ei, cnts);
  k_scan_a<<<SCAN_NB, 1024, 0, stream>>>(cnts, offs, bsum);
  k_scan_b<<<SCAN_NB, 1024, 0, stream>>>(bsum, offs, cnts);
  k_scatter<<<(NE + 255) / 256, 256, 0, stream>>>(ei, cnts, srcs);

  // x -> bf16
  k_cvt<<<(NN * 128 / 4 + 255) / 256, 256, 0, stream>>>(x, xb, NN * 128 / 4);

  // layer 1
  k_gather<128, true><<<(NN * 32 + 255) / 256, 256, 0, stream>>>(
      offs, srcs, xb, x, eps1, z1b);
  dim3 g1(391, 2);
  k_gemm<true, 0><<<g1, 256, 0, stream>>>(z1b, w1at, b1a, h1b, nullptr, NN, 128, 256);
  k_gemm<true, 0><<<g1, 256, 0, stream>>>(h1b, w1bt, b1b, hb, nullptr, NN, 256, 256);

  // layer 2
  k_gather<256, false><<<(NN * 64 + 255) / 256, 256, 0, stream>>>(
      offs, srcs, hb, hb, nullptr, z2b);
  k_gemm<true, 0><<<g1, 256, 0, stream>>>(z2b, w2t, b2, h2b, nullptr, NN, 256, 256);
  dim3 g4(391, 1);
  k_gemm<false, 2><<<g4, 256, 0, stream>>>(h2b, w3t, b3, nullptr, (float*)d_out, NN, 256, 128);
}